// Round 1
// baseline (3658.792 us; speedup 1.0000x reference)
//
#include <hip/hip_runtime.h>
#include <stdint.h>

// ---------------- problem constants ----------------
static constexpr int    N_NODES = 50000;
static constexpr int    N_EDGES = 800000;
static constexpr int    DIN     = 512;
static constexpr int    DOUT    = 128;
static constexpr size_t SEQ_ELEMS = (size_t)N_NODES * DIN;   // 25,600,000
static constexpr size_t H_ELEMS   = (size_t)N_NODES * DOUT;  //  6,400,000

// ---------------- threefry2x32 (20 rounds, JAX/Random123) ----------------
__device__ __forceinline__ uint32_t rotl32(uint32_t x, int r) {
  return (x << r) | (x >> (32 - r));
}

__device__ __forceinline__ void threefry2x32(uint32_t k0, uint32_t k1,
                                             uint32_t x0, uint32_t x1,
                                             uint32_t& o0, uint32_t& o1) {
  uint32_t ks0 = k0, ks1 = k1, ks2 = k0 ^ k1 ^ 0x1BD11BDAu;
  x0 += ks0; x1 += ks1;
#define TF_ROUND(r) { x0 += x1; x1 = rotl32(x1, (r)); x1 ^= x0; }
  TF_ROUND(13) TF_ROUND(15) TF_ROUND(26) TF_ROUND(6)
  x0 += ks1; x1 += ks2 + 1u;
  TF_ROUND(17) TF_ROUND(29) TF_ROUND(16) TF_ROUND(24)
  x0 += ks2; x1 += ks0 + 2u;
  TF_ROUND(13) TF_ROUND(15) TF_ROUND(26) TF_ROUND(6)
  x0 += ks0; x1 += ks1 + 3u;
  TF_ROUND(17) TF_ROUND(29) TF_ROUND(16) TF_ROUND(24)
  x0 += ks1; x1 += ks2 + 4u;
  TF_ROUND(13) TF_ROUND(15) TF_ROUND(26) TF_ROUND(6)
  x0 += ks2; x1 += ks0 + 5u;
#undef TF_ROUND
  o0 = x0; o1 = x1;
}

// partitionable threefry random_bits, bit_width=32: counter (hi=0, lo=i), xor both words
__device__ __forceinline__ uint32_t randbits32(uint32_t k0, uint32_t k1, uint32_t ctr) {
  uint32_t a, b;
  threefry2x32(k0, k1, 0u, ctr, a, b);
  return a ^ b;
}

// ---------------- key setup ----------------
// hdr[0..1]=k1(pos dropout) hdr[2..3]=k2(neg dropout)
// hdr[4..5]=sub1(shuffle round1 bits) hdr[6..7]=sub2(shuffle round2 bits)
// hdr[8]=keep_p bits, hdr[9]=scale bits
__global__ void setup_keys_kernel(const float* __restrict__ pprob, uint32_t* __restrict__ hdr) {
  if (threadIdx.x != 0 || blockIdx.x != 0) return;
  const uint32_t b0 = 0u, b1 = 1u;  // threefry_seed(1) = [0, 1]
  uint32_t k1a, k1b, k2a, k2b, k3a, k3b;
  threefry2x32(b0, b1, 0u, 0u, k1a, k1b);  // split(key(1),3)[0]
  threefry2x32(b0, b1, 0u, 1u, k2a, k2b);  // [1]
  threefry2x32(b0, b1, 0u, 2u, k3a, k3b);  // [2]
  // _shuffle: round1: key,sub1 = split(k3); round2: _,sub2 = split(key)
  uint32_t ra, rb, s1a, s1b, s2a, s2b;
  threefry2x32(k3a, k3b, 0u, 0u, ra, rb);
  threefry2x32(k3a, k3b, 0u, 1u, s1a, s1b);
  threefry2x32(ra, rb, 0u, 1u, s2a, s2b);
  hdr[0] = k1a; hdr[1] = k1b; hdr[2] = k2a; hdr[3] = k2b;
  hdr[4] = s1a; hdr[5] = s1b; hdr[6] = s2a; hdr[7] = s2b;
  float p = pprob[0];
  hdr[8] = __float_as_uint(1.0f - p);
  hdr[9] = __float_as_uint(1.0f / (1.0f - p));
}

// ---------------- dropout: out[i] = (uniform(bits_i) < keep_p) ? x[i]*scale : 0 ----------------
__global__ void dropout_kernel(const float* __restrict__ x, float* __restrict__ o,
                               const uint32_t* __restrict__ hdr, int keyoff, size_t nvec) {
  size_t t = (size_t)blockIdx.x * blockDim.x + threadIdx.x;
  if (t >= nvec) return;
  uint32_t k0 = hdr[keyoff], k1 = hdr[keyoff + 1];
  float keep_p = __uint_as_float(hdr[8]);
  float scale  = __uint_as_float(hdr[9]);
  size_t i = t * 4;
  float4 v = *reinterpret_cast<const float4*>(x + i);
  float r[4] = {v.x, v.y, v.z, v.w};
#pragma unroll
  for (int j = 0; j < 4; ++j) {
    uint32_t bits = randbits32(k0, k1, (uint32_t)(i + j));
    float u = __uint_as_float((bits >> 9) | 0x3f800000u) - 1.0f;
    r[j] = (u < keep_p) ? r[j] * scale : 0.0f;
  }
  *reinterpret_cast<float4*>(o + i) = make_float4(r[0], r[1], r[2], r[3]);
}

// ---------------- degree histogram / dinv / CSR ----------------
__global__ void deg_count_kernel(const int* __restrict__ ei, uint32_t* __restrict__ degcnt) {
  int e = blockIdx.x * blockDim.x + threadIdx.x;
  if (e >= N_EDGES) return;
  int d = ei[N_EDGES + e];  // dst
  atomicAdd(&degcnt[d], 1u);
}

__global__ void dinv_kernel(const uint32_t* __restrict__ degcnt, float* __restrict__ dinv) {
  int n = blockIdx.x * blockDim.x + threadIdx.x;
  if (n >= N_NODES) return;
  float deg = (float)(degcnt[n] + 1u);  // + self loop
  dinv[n] = 1.0f / sqrtf(deg);
}

__global__ void __launch_bounds__(1024) scan_kernel(const uint32_t* __restrict__ cnt,
                                                    uint32_t* __restrict__ rowptr, int n) {
  __shared__ uint32_t buf[1024];
  __shared__ uint32_t carry;
  int tid = threadIdx.x;
  if (tid == 0) carry = 0;
  __syncthreads();
  for (int base = 0; base < n; base += 1024) {
    int i = base + tid;
    uint32_t v = (i < n) ? cnt[i] : 0u;
    buf[tid] = v;
    __syncthreads();
    for (int off = 1; off < 1024; off <<= 1) {
      uint32_t t = (tid >= off) ? buf[tid - off] : 0u;
      __syncthreads();
      buf[tid] += t;
      __syncthreads();
    }
    uint32_t incl = buf[tid];
    uint32_t base_c = carry;
    if (i < n) rowptr[i] = base_c + incl - v;  // exclusive
    __syncthreads();
    if (tid == 1023) carry = base_c + buf[1023];
    __syncthreads();
  }
  if (tid == 0) rowptr[n] = carry;
}

__global__ void fill_kernel(const int* __restrict__ ei, const uint32_t* __restrict__ rowptr,
                            uint32_t* __restrict__ cursor, uint32_t* __restrict__ colsrc) {
  int e = blockIdx.x * blockDim.x + threadIdx.x;
  if (e >= N_EDGES) return;
  int s = ei[e];
  int d = ei[N_EDGES + e];
  uint32_t pos = rowptr[d] + atomicAdd(&cursor[d], 1u);
  colsrc[pos] = (uint32_t)s;
}

// ---------------- plain f32 tiled GEMM: C[M,128] = A[M,512] @ B[512,128] ----------------
// 64x64 tile per 256-thread block, 4x4 micro-tile per thread.
__global__ void __launch_bounds__(256) gemm_f32_kernel(const float* __restrict__ A,
                                                       const float* __restrict__ B,
                                                       float* __restrict__ C, int M) {
  constexpr int BM = 64, BN = 64, BK = 16;
  __shared__ float As[BK][BM + 1];
  __shared__ float Bs[BK][BN + 1];
  int tidx = threadIdx.x;
  int tx = tidx & 15, ty = tidx >> 4;
  int rowBase = blockIdx.x * BM;
  int colBase = blockIdx.y * BN;
  float acc[4][4] = {};
  for (int k0 = 0; k0 < DIN; k0 += BK) {
    {  // A tile: 64 rows x 16 k, float4 per thread
      int r  = tidx >> 2;
      int kq = (tidx & 3) * 4;
      int row = rowBase + r;
      float4 v = make_float4(0.f, 0.f, 0.f, 0.f);
      if (row < M) v = *reinterpret_cast<const float4*>(&A[(size_t)row * DIN + k0 + kq]);
      As[kq + 0][r] = v.x; As[kq + 1][r] = v.y; As[kq + 2][r] = v.z; As[kq + 3][r] = v.w;
    }
    {  // B tile: 16 k x 64 cols
      int kr = tidx >> 4;
      int c  = (tidx & 15) * 4;
      float4 v = *reinterpret_cast<const float4*>(&B[(size_t)(k0 + kr) * DOUT + colBase + c]);
      Bs[kr][c + 0] = v.x; Bs[kr][c + 1] = v.y; Bs[kr][c + 2] = v.z; Bs[kr][c + 3] = v.w;
    }
    __syncthreads();
#pragma unroll
    for (int kk = 0; kk < BK; ++kk) {
      float a0 = As[kk][ty * 4 + 0], a1 = As[kk][ty * 4 + 1];
      float a2 = As[kk][ty * 4 + 2], a3 = As[kk][ty * 4 + 3];
      float b0 = Bs[kk][tx * 4 + 0], b1 = Bs[kk][tx * 4 + 1];
      float b2 = Bs[kk][tx * 4 + 2], b3 = Bs[kk][tx * 4 + 3];
      acc[0][0] += a0 * b0; acc[0][1] += a0 * b1; acc[0][2] += a0 * b2; acc[0][3] += a0 * b3;
      acc[1][0] += a1 * b0; acc[1][1] += a1 * b1; acc[1][2] += a1 * b2; acc[1][3] += a1 * b3;
      acc[2][0] += a2 * b0; acc[2][1] += a2 * b1; acc[2][2] += a2 * b2; acc[2][3] += a2 * b3;
      acc[3][0] += a3 * b0; acc[3][1] += a3 * b1; acc[3][2] += a3 * b2; acc[3][3] += a3 * b3;
    }
    __syncthreads();
  }
#pragma unroll
  for (int i = 0; i < 4; ++i) {
    int row = rowBase + ty * 4 + i;
    if (row >= M) continue;
#pragma unroll
    for (int j = 0; j < 4; ++j) {
      C[(size_t)row * DOUT + colBase + tx * 4 + j] = acc[i][j];
    }
  }
}

// ---------------- permutation: keys + stable rank-by-count sort ----------------
__global__ void permkeys_kernel(const uint32_t* __restrict__ hdr, int keyoff,
                                uint32_t* __restrict__ keys, uint32_t* __restrict__ iota, int n) {
  int i = blockIdx.x * blockDim.x + threadIdx.x;
  if (i >= n) return;
  keys[i] = randbits32(hdr[keyoff], hdr[keyoff + 1], (uint32_t)i);
  if (iota) iota[i] = (uint32_t)i;
}

__global__ void ranksort_kernel(const uint32_t* __restrict__ keys, const uint32_t* __restrict__ vals,
                                uint32_t* __restrict__ outv, int n) {
  alignas(16) __shared__ uint32_t tile[1024];
  int i = blockIdx.x * blockDim.x + threadIdx.x;
  uint32_t ki = (i < n) ? keys[i] : 0u;
  int rank = 0;
  for (int base = 0; base < n; base += 1024) {
    int lim = n - base;  // may exceed 1024; pad with 0xFFFFFFFF
    for (int t = threadIdx.x; t < 1024; t += 256)
      tile[t] = (t < lim) ? keys[base + t] : 0xFFFFFFFFu;
    __syncthreads();
    if (i < n) {
#pragma unroll 4
      for (int t = 0; t < 1024; t += 4) {
        uint4 kv = *reinterpret_cast<const uint4*>(&tile[t]);
        int j0 = base + t;
        rank += (kv.x < ki) || (kv.x == ki && (j0 + 0) < i);
        rank += (kv.y < ki) || (kv.y == ki && (j0 + 1) < i);
        rank += (kv.z < ki) || (kv.z == ki && (j0 + 2) < i);
        rank += (kv.w < ki) || (kv.w == ki && (j0 + 3) < i);
      }
    }
    __syncthreads();
  }
  if (i < n) outv[rank] = vals[i];
}

// ---------------- GCN gather conv: out[n] = relu(dn*sum + dn^2*self + b) ----------------
template <bool USE_PERM>
__global__ void gcn_gather_kernel(const float* __restrict__ hw, const float* __restrict__ dinv,
                                  const uint32_t* __restrict__ rowptr,
                                  const uint32_t* __restrict__ colsrc,
                                  const uint32_t* __restrict__ perm,
                                  const float* __restrict__ bias,
                                  float* __restrict__ outh) {
  int n = blockIdx.x;
  int c = threadIdx.x;  // 0..127
  uint32_t e0 = rowptr[n], e1 = rowptr[n + 1];
  float acc = 0.0f;
  for (uint32_t e = e0; e < e1; ++e) {
    uint32_t s = colsrc[e];
    float dv = dinv[s];
    uint32_t srow = USE_PERM ? perm[s] : s;
    acc += hw[(size_t)srow * DOUT + c] * dv;
  }
  float dn = dinv[n];
  uint32_t nrow = USE_PERM ? perm[n] : (uint32_t)n;
  float self = hw[(size_t)nrow * DOUT + c];
  float v = dn * acc + dn * dn * self + bias[c];
  outh[(size_t)n * DOUT + c] = v > 0.0f ? v : 0.0f;
}

// ---------------- summary = sigmoid(mean(pos_h, axis=0)) ----------------
__global__ void colsum_kernel(const float* __restrict__ ph, float* __restrict__ sumbuf) {
  int c = threadIdx.x;  // 0..127
  int r0 = blockIdx.x * 256;
  int r1 = r0 + 256; if (r1 > N_NODES) r1 = N_NODES;
  float s = 0.0f;
  for (int r = r0; r < r1; ++r) s += ph[(size_t)r * DOUT + c];
  atomicAdd(&sumbuf[c], s);
}

__global__ void sigmoid_kernel(const float* __restrict__ sumbuf, float* __restrict__ outs) {
  int c = threadIdx.x;
  if (c >= DOUT) return;
  float m = sumbuf[c] * (1.0f / (float)N_NODES);
  outs[c] = 1.0f / (1.0f + expf(-m));
}

// ---------------- launch ----------------
extern "C" void kernel_launch(void* const* d_in, const int* in_sizes, int n_in,
                              void* d_out, int out_size, void* d_ws, size_t ws_size,
                              hipStream_t stream) {
  const float* x     = (const float*)d_in[0];
  const int*   ei    = (const int*)d_in[1];      // [2, E] int32 (harness int convention)
  const float* W     = (const float*)d_in[2];
  const float* bias  = (const float*)d_in[3];
  const float* pprob = (const float*)d_in[4];

  float* out = (float*)d_out;
  float* out_pos_h   = out;                          // 6,400,000
  float* out_neg_h   = out + H_ELEMS;                // 6,400,000
  float* out_summary = out + 2 * H_ELEMS;            // 128
  float* out_pos_seq = out + 2 * H_ELEMS + DOUT;     // 25,600,000
  float* out_neg_seq = out_pos_seq + SEQ_ELEMS;      // 25,600,000

  // ---- workspace layout (bytes) ----
  char* ws = (char*)d_ws;
  uint32_t* hdr     = (uint32_t*)(ws + 0);                        // 16 u32
  uint32_t* degcnt  = (uint32_t*)(ws + 64);                       // 50000
  uint32_t* cursor2 = (uint32_t*)(ws + 200064);                   // 50000
  float*    sumbuf  = (float*)   (ws + 400064);                   // 128
  uint32_t* rowptr  = (uint32_t*)(ws + 400576);                   // 50001
  uint32_t* colsrc  = (uint32_t*)(ws + 600592);                   // 800000
  float*    dinv    = (float*)   (ws + 3800592);                  // 50000
  uint32_t* keysA   = (uint32_t*)(ws + 4000592);                  // 50000
  uint32_t* x1      = (uint32_t*)(ws + 4200592);                  // 50000
  uint32_t* keysB   = (uint32_t*)(ws + 4400592);                  // 50000
  uint32_t* permv   = (uint32_t*)(ws + 4600592);                  // 50000
  uint32_t* valsA   = (uint32_t*)(ws + 4800592);                  // 50000
  float*    hw_pos  = (float*)   (ws + 5000592);                  // 6,400,000
  float*    hw_neg  = (float*)   (ws + 30600592);                 // 6,400,000

  // zero the atomic accumulators (degcnt, cursor2, sumbuf) in one memset
  hipMemsetAsync(ws + 64, 0, 400576 - 64, stream);

  setup_keys_kernel<<<1, 64, 0, stream>>>(pprob, hdr);

  // dropout -> pos_seq / neg_seq outputs
  dropout_kernel<<<(unsigned)(SEQ_ELEMS / 4 / 256), 256, 0, stream>>>(x, out_pos_seq, hdr, 0, SEQ_ELEMS / 4);
  dropout_kernel<<<(unsigned)(SEQ_ELEMS / 4 / 256), 256, 0, stream>>>(x, out_neg_seq, hdr, 2, SEQ_ELEMS / 4);

  // graph structure
  deg_count_kernel<<<(N_EDGES + 255) / 256, 256, 0, stream>>>(ei, degcnt);
  dinv_kernel<<<(N_NODES + 255) / 256, 256, 0, stream>>>(degcnt, dinv);
  scan_kernel<<<1, 1024, 0, stream>>>(degcnt, rowptr, N_NODES);
  fill_kernel<<<(N_EDGES + 255) / 256, 256, 0, stream>>>(ei, rowptr, cursor2, colsrc);

  // hw = seq @ W
  dim3 ggrid((N_NODES + 63) / 64, DOUT / 64);
  gemm_f32_kernel<<<ggrid, 256, 0, stream>>>(out_pos_seq, W, hw_pos, N_NODES);
  gemm_f32_kernel<<<ggrid, 256, 0, stream>>>(out_neg_seq, W, hw_neg, N_NODES);

  // permutation (2 stable sort rounds)
  int pblocks = (N_NODES + 255) / 256;
  permkeys_kernel<<<pblocks, 256, 0, stream>>>(hdr, 4, keysA, valsA, N_NODES);
  ranksort_kernel<<<pblocks, 256, 0, stream>>>(keysA, valsA, x1, N_NODES);
  permkeys_kernel<<<pblocks, 256, 0, stream>>>(hdr, 6, keysB, nullptr, N_NODES);
  ranksort_kernel<<<pblocks, 256, 0, stream>>>(keysB, x1, permv, N_NODES);

  // convs
  gcn_gather_kernel<false><<<N_NODES, DOUT, 0, stream>>>(hw_pos, dinv, rowptr, colsrc, nullptr, bias, out_pos_h);
  gcn_gather_kernel<true><<<N_NODES, DOUT, 0, stream>>>(hw_neg, dinv, rowptr, colsrc, permv, bias, out_neg_h);

  // summary
  colsum_kernel<<<(N_NODES + 255) / 256, DOUT, 0, stream>>>(out_pos_h, sumbuf);
  sigmoid_kernel<<<1, DOUT, 0, stream>>>(sumbuf, out_summary);

  (void)in_sizes; (void)n_in; (void)out_size; (void)ws_size;
}

// Round 2
// 1506.916 us; speedup vs baseline: 2.4280x; 2.4280x over previous
//
#include <hip/hip_runtime.h>
#include <stdint.h>

// ---------------- problem constants ----------------
static constexpr int    N_NODES = 50000;
static constexpr int    N_EDGES = 800000;
static constexpr int    DIN     = 512;
static constexpr int    DOUT    = 128;
static constexpr size_t SEQ_ELEMS = (size_t)N_NODES * DIN;   // 25,600,000
static constexpr size_t H_ELEMS   = (size_t)N_NODES * DOUT;  //  6,400,000

// radix sort geometry
static constexpr int RS_BLOCK   = 256;
static constexpr int RS_EPT     = 4;                                   // elems/thread
static constexpr int RS_TILE    = RS_BLOCK * RS_EPT;                   // 1024
static constexpr int RS_NBLOCKS = (N_NODES + RS_TILE - 1) / RS_TILE;   // 49

// ---------------- threefry2x32 (20 rounds, JAX/Random123) ----------------
__device__ __forceinline__ uint32_t rotl32(uint32_t x, int r) {
  return (x << r) | (x >> (32 - r));
}

__device__ __forceinline__ void threefry2x32(uint32_t k0, uint32_t k1,
                                             uint32_t x0, uint32_t x1,
                                             uint32_t& o0, uint32_t& o1) {
  uint32_t ks0 = k0, ks1 = k1, ks2 = k0 ^ k1 ^ 0x1BD11BDAu;
  x0 += ks0; x1 += ks1;
#define TF_ROUND(r) { x0 += x1; x1 = rotl32(x1, (r)); x1 ^= x0; }
  TF_ROUND(13) TF_ROUND(15) TF_ROUND(26) TF_ROUND(6)
  x0 += ks1; x1 += ks2 + 1u;
  TF_ROUND(17) TF_ROUND(29) TF_ROUND(16) TF_ROUND(24)
  x0 += ks2; x1 += ks0 + 2u;
  TF_ROUND(13) TF_ROUND(15) TF_ROUND(26) TF_ROUND(6)
  x0 += ks0; x1 += ks1 + 3u;
  TF_ROUND(17) TF_ROUND(29) TF_ROUND(16) TF_ROUND(24)
  x0 += ks1; x1 += ks2 + 4u;
  TF_ROUND(13) TF_ROUND(15) TF_ROUND(26) TF_ROUND(6)
  x0 += ks2; x1 += ks0 + 5u;
#undef TF_ROUND
  o0 = x0; o1 = x1;
}

// partitionable threefry random_bits, bit_width=32: counter (hi=0, lo=i), xor both words
__device__ __forceinline__ uint32_t randbits32(uint32_t k0, uint32_t k1, uint32_t ctr) {
  uint32_t a, b;
  threefry2x32(k0, k1, 0u, ctr, a, b);
  return a ^ b;
}

// ---------------- key setup ----------------
__global__ void setup_keys_kernel(const float* __restrict__ pprob, uint32_t* __restrict__ hdr) {
  if (threadIdx.x != 0 || blockIdx.x != 0) return;
  const uint32_t b0 = 0u, b1 = 1u;  // threefry_seed(1) = [0, 1]
  uint32_t k1a, k1b, k2a, k2b, k3a, k3b;
  threefry2x32(b0, b1, 0u, 0u, k1a, k1b);  // split(key(1),3)[0]
  threefry2x32(b0, b1, 0u, 1u, k2a, k2b);  // [1]
  threefry2x32(b0, b1, 0u, 2u, k3a, k3b);  // [2]
  uint32_t ra, rb, s1a, s1b, s2a, s2b;
  threefry2x32(k3a, k3b, 0u, 0u, ra, rb);   // round1 carry key
  threefry2x32(k3a, k3b, 0u, 1u, s1a, s1b); // round1 subkey
  threefry2x32(ra, rb, 0u, 1u, s2a, s2b);   // round2 subkey
  hdr[0] = k1a; hdr[1] = k1b; hdr[2] = k2a; hdr[3] = k2b;
  hdr[4] = s1a; hdr[5] = s1b; hdr[6] = s2a; hdr[7] = s2b;
  float p = pprob[0];
  hdr[8] = __float_as_uint(1.0f - p);
  hdr[9] = __float_as_uint(1.0f / (1.0f - p));
}

// ---------------- dropout ----------------
__global__ void dropout_kernel(const float* __restrict__ x, float* __restrict__ o,
                               const uint32_t* __restrict__ hdr, int keyoff, size_t nvec) {
  size_t t = (size_t)blockIdx.x * blockDim.x + threadIdx.x;
  if (t >= nvec) return;
  uint32_t k0 = hdr[keyoff], k1 = hdr[keyoff + 1];
  float keep_p = __uint_as_float(hdr[8]);
  float scale  = __uint_as_float(hdr[9]);
  size_t i = t * 4;
  float4 v = *reinterpret_cast<const float4*>(x + i);
  float r[4] = {v.x, v.y, v.z, v.w};
#pragma unroll
  for (int j = 0; j < 4; ++j) {
    uint32_t bits = randbits32(k0, k1, (uint32_t)(i + j));
    float u = __uint_as_float((bits >> 9) | 0x3f800000u) - 1.0f;
    r[j] = (u < keep_p) ? r[j] * scale : 0.0f;
  }
  *reinterpret_cast<float4*>(o + i) = make_float4(r[0], r[1], r[2], r[3]);
}

// ---------------- degree histogram / dinv / CSR ----------------
__global__ void deg_count_kernel(const int* __restrict__ ei, uint32_t* __restrict__ degcnt) {
  int e = blockIdx.x * blockDim.x + threadIdx.x;
  if (e >= N_EDGES) return;
  int d = ei[N_EDGES + e];  // dst
  atomicAdd(&degcnt[d], 1u);
}

__global__ void dinv_kernel(const uint32_t* __restrict__ degcnt, float* __restrict__ dinv) {
  int n = blockIdx.x * blockDim.x + threadIdx.x;
  if (n >= N_NODES) return;
  float deg = (float)(degcnt[n] + 1u);  // + self loop
  dinv[n] = 1.0f / sqrtf(deg);
}

__global__ void __launch_bounds__(1024) scan_kernel(const uint32_t* __restrict__ cnt,
                                                    uint32_t* __restrict__ rowptr, int n) {
  __shared__ uint32_t buf[1024];
  __shared__ uint32_t carry;
  int tid = threadIdx.x;
  if (tid == 0) carry = 0;
  __syncthreads();
  for (int base = 0; base < n; base += 1024) {
    int i = base + tid;
    uint32_t v = (i < n) ? cnt[i] : 0u;
    buf[tid] = v;
    __syncthreads();
    for (int off = 1; off < 1024; off <<= 1) {
      uint32_t t = (tid >= off) ? buf[tid - off] : 0u;
      __syncthreads();
      buf[tid] += t;
      __syncthreads();
    }
    uint32_t incl = buf[tid];
    uint32_t base_c = carry;
    if (i < n) rowptr[i] = base_c + incl - v;  // exclusive
    __syncthreads();
    if (tid == 1023) carry = base_c + buf[1023];
    __syncthreads();
  }
  if (tid == 0) rowptr[n] = carry;
}

__global__ void fill_kernel(const int* __restrict__ ei, const uint32_t* __restrict__ rowptr,
                            uint32_t* __restrict__ cursor, uint32_t* __restrict__ colsrc) {
  int e = blockIdx.x * blockDim.x + threadIdx.x;
  if (e >= N_EDGES) return;
  int s = ei[e];
  int d = ei[N_EDGES + e];
  uint32_t pos = rowptr[d] + atomicAdd(&cursor[d], 1u);
  colsrc[pos] = (uint32_t)s;
}

// ---------------- plain f32 tiled GEMM: C[M,128] = A[M,512] @ B[512,128] ----------------
__global__ void __launch_bounds__(256) gemm_f32_kernel(const float* __restrict__ A,
                                                       const float* __restrict__ B,
                                                       float* __restrict__ C, int M) {
  constexpr int BM = 64, BN = 64, BK = 16;
  __shared__ float As[BK][BM + 1];
  __shared__ float Bs[BK][BN + 1];
  int tidx = threadIdx.x;
  int tx = tidx & 15, ty = tidx >> 4;
  int rowBase = blockIdx.x * BM;
  int colBase = blockIdx.y * BN;
  float acc[4][4] = {};
  for (int k0 = 0; k0 < DIN; k0 += BK) {
    {
      int r  = tidx >> 2;
      int kq = (tidx & 3) * 4;
      int row = rowBase + r;
      float4 v = make_float4(0.f, 0.f, 0.f, 0.f);
      if (row < M) v = *reinterpret_cast<const float4*>(&A[(size_t)row * DIN + k0 + kq]);
      As[kq + 0][r] = v.x; As[kq + 1][r] = v.y; As[kq + 2][r] = v.z; As[kq + 3][r] = v.w;
    }
    {
      int kr = tidx >> 4;
      int c  = (tidx & 15) * 4;
      float4 v = *reinterpret_cast<const float4*>(&B[(size_t)(k0 + kr) * DOUT + colBase + c]);
      Bs[kr][c + 0] = v.x; Bs[kr][c + 1] = v.y; Bs[kr][c + 2] = v.z; Bs[kr][c + 3] = v.w;
    }
    __syncthreads();
#pragma unroll
    for (int kk = 0; kk < BK; ++kk) {
      float a0 = As[kk][ty * 4 + 0], a1 = As[kk][ty * 4 + 1];
      float a2 = As[kk][ty * 4 + 2], a3 = As[kk][ty * 4 + 3];
      float b0 = Bs[kk][tx * 4 + 0], b1 = Bs[kk][tx * 4 + 1];
      float b2 = Bs[kk][tx * 4 + 2], b3 = Bs[kk][tx * 4 + 3];
      acc[0][0] += a0 * b0; acc[0][1] += a0 * b1; acc[0][2] += a0 * b2; acc[0][3] += a0 * b3;
      acc[1][0] += a1 * b0; acc[1][1] += a1 * b1; acc[1][2] += a1 * b2; acc[1][3] += a1 * b3;
      acc[2][0] += a2 * b0; acc[2][1] += a2 * b1; acc[2][2] += a2 * b2; acc[2][3] += a2 * b3;
      acc[3][0] += a3 * b0; acc[3][1] += a3 * b1; acc[3][2] += a3 * b2; acc[3][3] += a3 * b3;
    }
    __syncthreads();
  }
#pragma unroll
  for (int i = 0; i < 4; ++i) {
    int row = rowBase + ty * 4 + i;
    if (row >= M) continue;
#pragma unroll
    for (int j = 0; j < 4; ++j) {
      C[(size_t)row * DOUT + colBase + tx * 4 + j] = acc[i][j];
    }
  }
}

// ---------------- permutation keys ----------------
__global__ void permkeys_kernel(const uint32_t* __restrict__ hdr, int keyoff,
                                uint32_t* __restrict__ keys, uint32_t* __restrict__ iota, int n) {
  int i = blockIdx.x * blockDim.x + threadIdx.x;
  if (i >= n) return;
  keys[i] = randbits32(hdr[keyoff], hdr[keyoff + 1], (uint32_t)i);
  if (iota) iota[i] = (uint32_t)i;
}

// ---------------- stable LSD radix sort (8-bit digits, 4 passes) ----------------
// hist layout is digit-major: hist[d * nblocks + b] so a flat exclusive scan
// yields stable global offsets.
__global__ void __launch_bounds__(RS_BLOCK) rs_hist_kernel(const uint32_t* __restrict__ keys,
                                                           uint32_t* __restrict__ hist,
                                                           int n, int shift) {
  __shared__ uint32_t h[256];
  int t = threadIdx.x;
  h[t] = 0;
  __syncthreads();
  int base = blockIdx.x * RS_TILE;
#pragma unroll
  for (int i = 0; i < RS_EPT; ++i) {
    int p = base + t + i * RS_BLOCK;
    if (p < n) atomicAdd(&h[(keys[p] >> shift) & 255u], 1u);
  }
  __syncthreads();
  hist[t * gridDim.x + blockIdx.x] = h[t];
}

__global__ void __launch_bounds__(256) rs_scan_kernel(const uint32_t* __restrict__ hist,
                                                      uint32_t* __restrict__ offs, int nblocks) {
  __shared__ uint32_t s[256];
  int d = threadIdx.x;
  uint32_t sum = 0;
  for (int b = 0; b < nblocks; ++b) sum += hist[d * nblocks + b];
  s[d] = sum;
  __syncthreads();
  for (int off = 1; off < 256; off <<= 1) {
    uint32_t t = (d >= off) ? s[d - off] : 0u;
    __syncthreads();
    s[d] += t;
    __syncthreads();
  }
  uint32_t run = s[d] - sum;  // exclusive prefix across digits
  for (int b = 0; b < nblocks; ++b) {
    uint32_t h = hist[d * nblocks + b];
    offs[d * nblocks + b] = run;
    run += h;
  }
}

__global__ void __launch_bounds__(RS_BLOCK) rs_scatter_kernel(const uint32_t* __restrict__ keys,
                                                              const uint32_t* __restrict__ vals,
                                                              const uint32_t* __restrict__ offs,
                                                              uint32_t* __restrict__ keys_out,
                                                              uint32_t* __restrict__ vals_out,
                                                              int n, int shift) {
  __shared__ uint16_t dig[RS_TILE];
  int t = threadIdx.x;
  int base = blockIdx.x * RS_TILE;
  uint32_t myk[RS_EPT];
  uint32_t myd[RS_EPT];
#pragma unroll
  for (int i = 0; i < RS_EPT; ++i) {
    int p = base + t + i * RS_BLOCK;
    if (p < n) {
      myk[i] = keys[p];
      myd[i] = (myk[i] >> shift) & 255u;
    } else {
      myk[i] = 0u;
      myd[i] = 0xFFFFu;  // sentinel, matches nothing real
    }
    dig[t + i * RS_BLOCK] = (uint16_t)myd[i];
  }
  __syncthreads();
  int rank[RS_EPT] = {0, 0, 0, 0};
  for (int j = 0; j < RS_TILE; ++j) {
    uint32_t dj = dig[j];  // same address across lanes -> LDS broadcast
#pragma unroll
    for (int i = 0; i < RS_EPT; ++i) {
      rank[i] += (j < t + i * RS_BLOCK) && (dj == myd[i]);
    }
  }
#pragma unroll
  for (int i = 0; i < RS_EPT; ++i) {
    int p = base + t + i * RS_BLOCK;
    if (p < n) {
      uint32_t pos = offs[myd[i] * gridDim.x + blockIdx.x] + (uint32_t)rank[i];
      keys_out[pos] = myk[i];
      vals_out[pos] = vals[p];
    }
  }
}

// ---------------- GCN gather conv ----------------
template <bool USE_PERM>
__global__ void gcn_gather_kernel(const float* __restrict__ hw, const float* __restrict__ dinv,
                                  const uint32_t* __restrict__ rowptr,
                                  const uint32_t* __restrict__ colsrc,
                                  const uint32_t* __restrict__ perm,
                                  const float* __restrict__ bias,
                                  float* __restrict__ outh) {
  int n = blockIdx.x;
  int c = threadIdx.x;  // 0..127
  uint32_t e0 = rowptr[n], e1 = rowptr[n + 1];
  float acc = 0.0f;
  for (uint32_t e = e0; e < e1; ++e) {
    uint32_t s = colsrc[e];
    float dv = dinv[s];
    uint32_t srow = USE_PERM ? perm[s] : s;
    acc += hw[(size_t)srow * DOUT + c] * dv;
  }
  float dn = dinv[n];
  uint32_t nrow = USE_PERM ? perm[n] : (uint32_t)n;
  float self = hw[(size_t)nrow * DOUT + c];
  float v = dn * acc + dn * dn * self + bias[c];
  outh[(size_t)n * DOUT + c] = v > 0.0f ? v : 0.0f;
}

// ---------------- summary ----------------
__global__ void colsum_kernel(const float* __restrict__ ph, float* __restrict__ sumbuf) {
  int c = threadIdx.x;
  int r0 = blockIdx.x * 256;
  int r1 = r0 + 256; if (r1 > N_NODES) r1 = N_NODES;
  float s = 0.0f;
  for (int r = r0; r < r1; ++r) s += ph[(size_t)r * DOUT + c];
  atomicAdd(&sumbuf[c], s);
}

__global__ void sigmoid_kernel(const float* __restrict__ sumbuf, float* __restrict__ outs) {
  int c = threadIdx.x;
  if (c >= DOUT) return;
  float m = sumbuf[c] * (1.0f / (float)N_NODES);
  outs[c] = 1.0f / (1.0f + expf(-m));
}

// ---------------- launch ----------------
extern "C" void kernel_launch(void* const* d_in, const int* in_sizes, int n_in,
                              void* d_out, int out_size, void* d_ws, size_t ws_size,
                              hipStream_t stream) {
  const float* x     = (const float*)d_in[0];
  const int*   ei    = (const int*)d_in[1];
  const float* W     = (const float*)d_in[2];
  const float* bias  = (const float*)d_in[3];
  const float* pprob = (const float*)d_in[4];

  float* out = (float*)d_out;
  float* out_pos_h   = out;                          // 6,400,000
  float* out_neg_h   = out + H_ELEMS;                // 6,400,000
  float* out_summary = out + 2 * H_ELEMS;            // 128
  float* out_pos_seq = out + 2 * H_ELEMS + DOUT;     // 25,600,000
  float* out_neg_seq = out_pos_seq + SEQ_ELEMS;      // 25,600,000

  // ---- workspace layout (bytes) ----
  char* ws = (char*)d_ws;
  uint32_t* hdr     = (uint32_t*)(ws + 0);        // 16 u32
  uint32_t* degcnt  = (uint32_t*)(ws + 64);       // 50000 u32; reused as radix offs after CSR
  uint32_t* cursor2 = (uint32_t*)(ws + 200064);   // 50000 u32; reused as radix hist after CSR
  float*    sumbuf  = (float*)   (ws + 400064);   // 128
  uint32_t* rowptr  = (uint32_t*)(ws + 400576);   // 50001
  uint32_t* colsrc  = (uint32_t*)(ws + 600592);   // 800000
  float*    dinv    = (float*)   (ws + 3800592);  // 50000
  uint32_t* kA      = (uint32_t*)(ws + 4000592);  // 50000 (radix key ping)
  uint32_t* vB      = (uint32_t*)(ws + 4200592);  // 50000 (radix val pong)
  uint32_t* kB      = (uint32_t*)(ws + 4400592);  // 50000 (radix key pong)
  uint32_t* vA      = (uint32_t*)(ws + 4600592);  // 50000 (radix val ping; final perm)
  // ws + 4800592 .. 5000592 free (was valsA)
  float*    hw_pos  = (float*)   (ws + 5000592);  // 6,400,000
  float*    hw_neg  = (float*)   (ws + 30600592); // 6,400,000

  uint32_t* rs_hist = cursor2;   // 12544 u32, reused after fill_kernel
  uint32_t* rs_offs = degcnt;    // 12544 u32, reused after dinv/scan

  hipMemsetAsync(ws + 64, 0, 400576 - 64, stream);

  setup_keys_kernel<<<1, 64, 0, stream>>>(pprob, hdr);

  dropout_kernel<<<(unsigned)(SEQ_ELEMS / 4 / 256), 256, 0, stream>>>(x, out_pos_seq, hdr, 0, SEQ_ELEMS / 4);
  dropout_kernel<<<(unsigned)(SEQ_ELEMS / 4 / 256), 256, 0, stream>>>(x, out_neg_seq, hdr, 2, SEQ_ELEMS / 4);

  deg_count_kernel<<<(N_EDGES + 255) / 256, 256, 0, stream>>>(ei, degcnt);
  dinv_kernel<<<(N_NODES + 255) / 256, 256, 0, stream>>>(degcnt, dinv);
  scan_kernel<<<1, 1024, 0, stream>>>(degcnt, rowptr, N_NODES);
  fill_kernel<<<(N_EDGES + 255) / 256, 256, 0, stream>>>(ei, rowptr, cursor2, colsrc);

  dim3 ggrid((N_NODES + 63) / 64, DOUT / 64);
  gemm_f32_kernel<<<ggrid, 256, 0, stream>>>(out_pos_seq, W, hw_pos, N_NODES);
  gemm_f32_kernel<<<ggrid, 256, 0, stream>>>(out_neg_seq, W, hw_neg, N_NODES);

  // ---- permutation: 2 rounds of stable radix sort by fresh random keys ----
  int pblocks = (N_NODES + 255) / 256;
  permkeys_kernel<<<pblocks, 256, 0, stream>>>(hdr, 4, kA, vA, N_NODES);  // keys + iota
  for (int round = 0; round < 2; ++round) {
    if (round == 1)  // regenerate keys in kA; vA already holds round-1 result
      permkeys_kernel<<<pblocks, 256, 0, stream>>>(hdr, 6, kA, nullptr, N_NODES);
    for (int pass = 0; pass < 4; ++pass) {
      int shift = pass * 8;
      const uint32_t* ki = (pass & 1) ? kB : kA;
      const uint32_t* vi = (pass & 1) ? vB : vA;
      uint32_t* ko = (pass & 1) ? kA : kB;
      uint32_t* vo = (pass & 1) ? vA : vB;
      rs_hist_kernel<<<RS_NBLOCKS, RS_BLOCK, 0, stream>>>(ki, rs_hist, N_NODES, shift);
      rs_scan_kernel<<<1, 256, 0, stream>>>(rs_hist, rs_offs, RS_NBLOCKS);
      rs_scatter_kernel<<<RS_NBLOCKS, RS_BLOCK, 0, stream>>>(ki, vi, rs_offs, ko, vo, N_NODES, shift);
    }
    // after 4 passes result is back in kA / vA
  }
  const uint32_t* permv = vA;

  gcn_gather_kernel<false><<<N_NODES, DOUT, 0, stream>>>(hw_pos, dinv, rowptr, colsrc, nullptr, bias, out_pos_h);
  gcn_gather_kernel<true><<<N_NODES, DOUT, 0, stream>>>(hw_neg, dinv, rowptr, colsrc, permv, bias, out_neg_h);

  colsum_kernel<<<(N_NODES + 255) / 256, DOUT, 0, stream>>>(out_pos_h, sumbuf);
  sigmoid_kernel<<<1, DOUT, 0, stream>>>(sumbuf, out_summary);

  (void)in_sizes; (void)n_in; (void)out_size; (void)ws_size;
}

// Round 3
// 1147.611 us; speedup vs baseline: 3.1882x; 1.3131x over previous
//
#include <hip/hip_runtime.h>
#include <stdint.h>

// ---------------- problem constants ----------------
static constexpr int    N_NODES = 50000;
static constexpr int    N_EDGES = 800000;
static constexpr int    DIN     = 512;
static constexpr int    DOUT    = 128;
static constexpr size_t SEQ_ELEMS = (size_t)N_NODES * DIN;   // 25,600,000
static constexpr size_t H_ELEMS   = (size_t)N_NODES * DOUT;  //  6,400,000

// radix sort geometry
static constexpr int RS_BLOCK   = 256;
static constexpr int RS_EPT     = 4;
static constexpr int RS_TILE    = RS_BLOCK * RS_EPT;                   // 1024
static constexpr int RS_NBLOCKS = (N_NODES + RS_TILE - 1) / RS_TILE;   // 49

typedef __attribute__((ext_vector_type(8))) short bf16x8;
typedef __attribute__((ext_vector_type(4))) float f32x4;
typedef __attribute__((ext_vector_type(4))) unsigned short u16x4;

// f32 -> bf16 round-to-nearest-even
__device__ __forceinline__ uint16_t f2bf(float f) {
  uint32_t u = __float_as_uint(f);
  return (uint16_t)((u + 0x7FFFu + ((u >> 16) & 1u)) >> 16);
}

// ---------------- threefry2x32 (20 rounds, JAX/Random123) ----------------
__device__ __forceinline__ uint32_t rotl32(uint32_t x, int r) {
  return (x << r) | (x >> (32 - r));
}

__device__ __forceinline__ void threefry2x32(uint32_t k0, uint32_t k1,
                                             uint32_t x0, uint32_t x1,
                                             uint32_t& o0, uint32_t& o1) {
  uint32_t ks0 = k0, ks1 = k1, ks2 = k0 ^ k1 ^ 0x1BD11BDAu;
  x0 += ks0; x1 += ks1;
#define TF_ROUND(r) { x0 += x1; x1 = rotl32(x1, (r)); x1 ^= x0; }
  TF_ROUND(13) TF_ROUND(15) TF_ROUND(26) TF_ROUND(6)
  x0 += ks1; x1 += ks2 + 1u;
  TF_ROUND(17) TF_ROUND(29) TF_ROUND(16) TF_ROUND(24)
  x0 += ks2; x1 += ks0 + 2u;
  TF_ROUND(13) TF_ROUND(15) TF_ROUND(26) TF_ROUND(6)
  x0 += ks0; x1 += ks1 + 3u;
  TF_ROUND(17) TF_ROUND(29) TF_ROUND(16) TF_ROUND(24)
  x0 += ks1; x1 += ks2 + 4u;
  TF_ROUND(13) TF_ROUND(15) TF_ROUND(26) TF_ROUND(6)
  x0 += ks2; x1 += ks0 + 5u;
#undef TF_ROUND
  o0 = x0; o1 = x1;
}

__device__ __forceinline__ uint32_t randbits32(uint32_t k0, uint32_t k1, uint32_t ctr) {
  uint32_t a, b;
  threefry2x32(k0, k1, 0u, ctr, a, b);
  return a ^ b;
}

// ---------------- key setup ----------------
__global__ void setup_keys_kernel(const float* __restrict__ pprob, uint32_t* __restrict__ hdr) {
  if (threadIdx.x != 0 || blockIdx.x != 0) return;
  const uint32_t b0 = 0u, b1 = 1u;  // threefry_seed(1) = [0, 1]
  uint32_t k1a, k1b, k2a, k2b, k3a, k3b;
  threefry2x32(b0, b1, 0u, 0u, k1a, k1b);
  threefry2x32(b0, b1, 0u, 1u, k2a, k2b);
  threefry2x32(b0, b1, 0u, 2u, k3a, k3b);
  uint32_t ra, rb, s1a, s1b, s2a, s2b;
  threefry2x32(k3a, k3b, 0u, 0u, ra, rb);   // round1 carry key
  threefry2x32(k3a, k3b, 0u, 1u, s1a, s1b); // round1 subkey
  threefry2x32(ra, rb, 0u, 1u, s2a, s2b);   // round2 subkey
  hdr[0] = k1a; hdr[1] = k1b; hdr[2] = k2a; hdr[3] = k2b;
  hdr[4] = s1a; hdr[5] = s1b; hdr[6] = s2a; hdr[7] = s2b;
  float p = pprob[0];
  hdr[8] = __float_as_uint(1.0f - p);
  hdr[9] = __float_as_uint(1.0f / (1.0f - p));
}

// ---------------- dropout ----------------
__global__ void dropout_kernel(const float* __restrict__ x, float* __restrict__ o,
                               const uint32_t* __restrict__ hdr, int keyoff, size_t nvec) {
  size_t t = (size_t)blockIdx.x * blockDim.x + threadIdx.x;
  if (t >= nvec) return;
  uint32_t k0 = hdr[keyoff], k1 = hdr[keyoff + 1];
  float keep_p = __uint_as_float(hdr[8]);
  float scale  = __uint_as_float(hdr[9]);
  size_t i = t * 4;
  float4 v = *reinterpret_cast<const float4*>(x + i);
  float r[4] = {v.x, v.y, v.z, v.w};
#pragma unroll
  for (int j = 0; j < 4; ++j) {
    uint32_t bits = randbits32(k0, k1, (uint32_t)(i + j));
    float u = __uint_as_float((bits >> 9) | 0x3f800000u) - 1.0f;
    r[j] = (u < keep_p) ? r[j] * scale : 0.0f;
  }
  *reinterpret_cast<float4*>(o + i) = make_float4(r[0], r[1], r[2], r[3]);
}

// ---------------- W (512x128 f32) -> BT (128x512 bf16) ----------------
__global__ void __launch_bounds__(256) wt_bf16_kernel(const float* __restrict__ W,
                                                      uint16_t* __restrict__ BT) {
  __shared__ float tile[32][129];
  int k0 = blockIdx.x * 32;
  int t = threadIdx.x;
  for (int i = t; i < 32 * 128; i += 256) {
    int k = i >> 7, n = i & 127;
    tile[k][n] = W[(size_t)(k0 + k) * DOUT + n];
  }
  __syncthreads();
  for (int i = t; i < 32 * 128; i += 256) {
    int n = i >> 5, k = i & 31;
    BT[(size_t)n * DIN + k0 + k] = f2bf(tile[k][n]);
  }
}

// ---------------- degree histogram / dinv / CSR ----------------
__global__ void deg_count_kernel(const int* __restrict__ ei, uint32_t* __restrict__ degcnt) {
  int e = blockIdx.x * blockDim.x + threadIdx.x;
  if (e >= N_EDGES) return;
  int d = ei[N_EDGES + e];  // dst
  atomicAdd(&degcnt[d], 1u);
}

__global__ void dinv_kernel(const uint32_t* __restrict__ degcnt, float* __restrict__ dinv) {
  int n = blockIdx.x * blockDim.x + threadIdx.x;
  if (n >= N_NODES) return;
  float deg = (float)(degcnt[n] + 1u);  // + self loop
  dinv[n] = 1.0f / sqrtf(deg);
}

// hierarchical exclusive scan over degcnt -> rowptr
__global__ void __launch_bounds__(256) scan1_kernel(const uint32_t* __restrict__ cnt,
                                                    uint32_t* __restrict__ excl,
                                                    uint32_t* __restrict__ blksum, int n) {
  __shared__ uint32_t s[256];
  int t = threadIdx.x;
  int i = blockIdx.x * 256 + t;
  uint32_t v = (i < n) ? cnt[i] : 0u;
  s[t] = v;
  __syncthreads();
  for (int off = 1; off < 256; off <<= 1) {
    uint32_t x = (t >= off) ? s[t - off] : 0u;
    __syncthreads();
    s[t] += x;
    __syncthreads();
  }
  if (i < n) excl[i] = s[t] - v;
  if (t == 255) blksum[blockIdx.x] = s[255];
}

__global__ void __launch_bounds__(256) scan2_kernel(uint32_t* __restrict__ blksum, int nb) {
  __shared__ uint32_t s[256];
  int t = threadIdx.x;
  uint32_t v = (t < nb) ? blksum[t] : 0u;
  s[t] = v;
  __syncthreads();
  for (int off = 1; off < 256; off <<= 1) {
    uint32_t x = (t >= off) ? s[t - off] : 0u;
    __syncthreads();
    s[t] += x;
    __syncthreads();
  }
  if (t < nb) blksum[t] = s[t] - v;  // exclusive block offsets
}

__global__ void __launch_bounds__(256) scan3_kernel(uint32_t* __restrict__ excl,
                                                    const uint32_t* __restrict__ blkoff, int n) {
  int i = blockIdx.x * 256 + threadIdx.x;
  if (i < n) excl[i] += blkoff[i >> 8];
  if (i == 0) excl[n] = (uint32_t)N_EDGES;
}

__global__ void fill_kernel(const int* __restrict__ ei, const uint32_t* __restrict__ rowptr,
                            uint32_t* __restrict__ cursor, uint32_t* __restrict__ colsrc) {
  int e = blockIdx.x * blockDim.x + threadIdx.x;
  if (e >= N_EDGES) return;
  int s = ei[e];
  int d = ei[N_EDGES + e];
  uint32_t pos = rowptr[d] + atomicAdd(&cursor[d], 1u);
  colsrc[pos] = (uint32_t)s;
}

// ---------------- MFMA bf16 GEMM: C[M,128] = Af[M,512] @ W, via BT bf16 ----------------
// BM=64, BN=128(=DOUT), BK=64. 256 threads = 4 waves on 2x2 wave grid.
// A: reg-staged f32->bf16 into LDS [64][64]; B: global_load_lds from BT into LDS [128][64].
__global__ void __launch_bounds__(256) gemm_bf16_kernel(const float* __restrict__ Af,
                                                        const uint16_t* __restrict__ BT,
                                                        float* __restrict__ C, int M) {
  __shared__ __align__(16) uint16_t ldsA[64 * 64];
  __shared__ __align__(16) uint16_t ldsB[128 * 64];
  const int tid  = threadIdx.x;
  const int lane = tid & 63;
  const int w    = tid >> 6;
  const int wr   = w >> 1, wc = w & 1;
  const int m0   = blockIdx.x * 64;
  const int l15  = lane & 15, l4 = lane >> 4;
  const int lr   = lane >> 3, lk = (lane & 7) * 8;

  f32x4 acc[2][4] = {};

  for (int k0 = 0; k0 < DIN; k0 += 64) {
    // B tile: async global->LDS, 4 issues per wave (8 rows x 128B each)
#pragma unroll
    for (int s = 0; s < 4; ++s) {
      int nbase = w * 32 + s * 8;
      const uint16_t* gp = BT + (size_t)(nbase + lr) * DIN + k0 + lk;
      __builtin_amdgcn_global_load_lds(
          (const __attribute__((address_space(1))) void*)gp,
          (__attribute__((address_space(3))) void*)(ldsB + nbase * 64), 16, 0, 0);
    }
    // A tile: load f32x4, convert, ds_write as bf16x4 (8B)
    float4 av[4];
    int rowv[4], qv[4];
#pragma unroll
    for (int i = 0; i < 4; ++i) {
      int idx = tid + i * 256;
      int row = idx >> 4, q = idx & 15;
      int grow = m0 + row; if (grow > M - 1) grow = M - 1;  // clamp tail (data discarded)
      av[i] = *reinterpret_cast<const float4*>(Af + (size_t)grow * DIN + k0 + q * 4);
      rowv[i] = row; qv[i] = q;
    }
#pragma unroll
    for (int i = 0; i < 4; ++i) {
      u16x4 h;
      h.x = f2bf(av[i].x); h.y = f2bf(av[i].y); h.z = f2bf(av[i].z); h.w = f2bf(av[i].w);
      *reinterpret_cast<u16x4*>(ldsA + rowv[i] * 64 + qv[i] * 4) = h;
    }
    asm volatile("s_waitcnt vmcnt(0)" ::: "memory");
    __syncthreads();
#pragma unroll
    for (int kk = 0; kk < 2; ++kk) {
      bf16x8 afr[2], bfr[4];
#pragma unroll
      for (int f = 0; f < 2; ++f)
        afr[f] = *reinterpret_cast<const bf16x8*>(ldsA + (wr * 32 + f * 16 + l15) * 64 + kk * 32 + l4 * 8);
#pragma unroll
      for (int f = 0; f < 4; ++f)
        bfr[f] = *reinterpret_cast<const bf16x8*>(ldsB + (wc * 64 + f * 16 + l15) * 64 + kk * 32 + l4 * 8);
#pragma unroll
      for (int fm = 0; fm < 2; ++fm)
#pragma unroll
        for (int fn = 0; fn < 4; ++fn)
          acc[fm][fn] = __builtin_amdgcn_mfma_f32_16x16x32_bf16(afr[fm], bfr[fn], acc[fm][fn], 0, 0, 0);
    }
    __syncthreads();
  }
  // C/D layout: row = (lane>>4)*4 + r, col = lane&15 (m89-verified)
#pragma unroll
  for (int fm = 0; fm < 2; ++fm) {
#pragma unroll
    for (int r = 0; r < 4; ++r) {
      int row = m0 + wr * 32 + fm * 16 + l4 * 4 + r;
      if (row < M) {
        float* cp = C + (size_t)row * DOUT + wc * 64 + l15;
#pragma unroll
        for (int fn = 0; fn < 4; ++fn)
          cp[fn * 16] = acc[fm][fn][r];
      }
    }
  }
}

// ---------------- permutation keys ----------------
__global__ void permkeys_kernel(const uint32_t* __restrict__ hdr, int keyoff,
                                uint32_t* __restrict__ keys, uint32_t* __restrict__ iota, int n) {
  int i = blockIdx.x * blockDim.x + threadIdx.x;
  if (i >= n) return;
  keys[i] = randbits32(hdr[keyoff], hdr[keyoff + 1], (uint32_t)i);
  if (iota) iota[i] = (uint32_t)i;
}

// ---------------- stable LSD radix sort (8-bit digits, 4 passes) ----------------
__global__ void __launch_bounds__(RS_BLOCK) rs_hist_kernel(const uint32_t* __restrict__ keys,
                                                           uint32_t* __restrict__ hist,
                                                           int n, int shift) {
  __shared__ uint32_t h[256];
  int t = threadIdx.x;
  h[t] = 0;
  __syncthreads();
  int base = blockIdx.x * RS_TILE;
#pragma unroll
  for (int i = 0; i < RS_EPT; ++i) {
    int p = base + t + i * RS_BLOCK;
    if (p < n) atomicAdd(&h[(keys[p] >> shift) & 255u], 1u);
  }
  __syncthreads();
  hist[t * gridDim.x + blockIdx.x] = h[t];
}

__global__ void __launch_bounds__(256) rs_scan_kernel(const uint32_t* __restrict__ hist,
                                                      uint32_t* __restrict__ offs, int nblocks) {
  __shared__ uint32_t s[256];
  int d = threadIdx.x;
  uint32_t sum = 0;
  for (int b = 0; b < nblocks; ++b) sum += hist[d * nblocks + b];
  s[d] = sum;
  __syncthreads();
  for (int off = 1; off < 256; off <<= 1) {
    uint32_t t = (d >= off) ? s[d - off] : 0u;
    __syncthreads();
    s[d] += t;
    __syncthreads();
  }
  uint32_t run = s[d] - sum;
  for (int b = 0; b < nblocks; ++b) {
    uint32_t h = hist[d * nblocks + b];
    offs[d * nblocks + b] = run;
    run += h;
  }
}

__global__ void __launch_bounds__(RS_BLOCK) rs_scatter_kernel(const uint32_t* __restrict__ keys,
                                                              const uint32_t* __restrict__ vals,
                                                              const uint32_t* __restrict__ offs,
                                                              uint32_t* __restrict__ keys_out,
                                                              uint32_t* __restrict__ vals_out,
                                                              int n, int shift) {
  __shared__ uint16_t dig[RS_TILE];
  int t = threadIdx.x;
  int base = blockIdx.x * RS_TILE;
  uint32_t myk[RS_EPT];
  uint32_t myd[RS_EPT];
#pragma unroll
  for (int i = 0; i < RS_EPT; ++i) {
    int p = base + t + i * RS_BLOCK;
    if (p < n) {
      myk[i] = keys[p];
      myd[i] = (myk[i] >> shift) & 255u;
    } else {
      myk[i] = 0u;
      myd[i] = 0xFFFFu;
    }
    dig[t + i * RS_BLOCK] = (uint16_t)myd[i];
  }
  __syncthreads();
  int rank[RS_EPT] = {0, 0, 0, 0};
  for (int j = 0; j < RS_TILE; ++j) {
    uint32_t dj = dig[j];
#pragma unroll
    for (int i = 0; i < RS_EPT; ++i) {
      rank[i] += (j < t + i * RS_BLOCK) && (dj == myd[i]);
    }
  }
#pragma unroll
  for (int i = 0; i < RS_EPT; ++i) {
    int p = base + t + i * RS_BLOCK;
    if (p < n) {
      uint32_t pos = offs[myd[i] * gridDim.x + blockIdx.x] + (uint32_t)rank[i];
      keys_out[pos] = myk[i];
      vals_out[pos] = vals[p];
    }
  }
}

// ---------------- GCN gather conv (float4 per lane, 8 nodes/block) ----------------
template <bool USE_PERM>
__global__ void __launch_bounds__(256) gcn_gather_kernel(const float* __restrict__ hw,
                                                         const float* __restrict__ dinv,
                                                         const uint32_t* __restrict__ rowptr,
                                                         const uint32_t* __restrict__ colsrc,
                                                         const uint32_t* __restrict__ perm,
                                                         const float* __restrict__ bias,
                                                         float* __restrict__ outh) {
  int node = blockIdx.x * 8 + (threadIdx.x >> 5);
  if (node >= N_NODES) return;
  int c4 = (threadIdx.x & 31) * 4;
  uint32_t e0 = rowptr[node], e1 = rowptr[node + 1];
  float ax = 0.f, ay = 0.f, az = 0.f, aw = 0.f;
  for (uint32_t e = e0; e < e1; ++e) {
    uint32_t s = colsrc[e];
    float dv = dinv[s];
    uint32_t srow = USE_PERM ? perm[s] : s;
    float4 v = *reinterpret_cast<const float4*>(hw + (size_t)srow * DOUT + c4);
    ax += v.x * dv; ay += v.y * dv; az += v.z * dv; aw += v.w * dv;
  }
  float dn = dinv[node];
  uint32_t nrow = USE_PERM ? perm[node] : (uint32_t)node;
  float4 sv = *reinterpret_cast<const float4*>(hw + (size_t)nrow * DOUT + c4);
  float4 bv = *reinterpret_cast<const float4*>(bias + c4);
  float d2 = dn * dn;
  float4 o;
  o.x = fmaxf(dn * ax + d2 * sv.x + bv.x, 0.0f);
  o.y = fmaxf(dn * ay + d2 * sv.y + bv.y, 0.0f);
  o.z = fmaxf(dn * az + d2 * sv.z + bv.z, 0.0f);
  o.w = fmaxf(dn * aw + d2 * sv.w + bv.w, 0.0f);
  *reinterpret_cast<float4*>(outh + (size_t)node * DOUT + c4) = o;
}

// ---------------- summary ----------------
__global__ void colsum_kernel(const float* __restrict__ ph, float* __restrict__ sumbuf) {
  int c = threadIdx.x;
  int r0 = blockIdx.x * 256;
  int r1 = r0 + 256; if (r1 > N_NODES) r1 = N_NODES;
  float s = 0.0f;
  for (int r = r0; r < r1; ++r) s += ph[(size_t)r * DOUT + c];
  atomicAdd(&sumbuf[c], s);
}

__global__ void sigmoid_kernel(const float* __restrict__ sumbuf, float* __restrict__ outs) {
  int c = threadIdx.x;
  if (c >= DOUT) return;
  float m = sumbuf[c] * (1.0f / (float)N_NODES);
  outs[c] = 1.0f / (1.0f + expf(-m));
}

// ---------------- launch ----------------
extern "C" void kernel_launch(void* const* d_in, const int* in_sizes, int n_in,
                              void* d_out, int out_size, void* d_ws, size_t ws_size,
                              hipStream_t stream) {
  const float* x     = (const float*)d_in[0];
  const int*   ei    = (const int*)d_in[1];
  const float* W     = (const float*)d_in[2];
  const float* bias  = (const float*)d_in[3];
  const float* pprob = (const float*)d_in[4];

  float* out = (float*)d_out;
  float* out_pos_h   = out;                          // 6,400,000
  float* out_neg_h   = out + H_ELEMS;                // 6,400,000
  float* out_summary = out + 2 * H_ELEMS;            // 128
  float* out_pos_seq = out + 2 * H_ELEMS + DOUT;     // 25,600,000
  float* out_neg_seq = out_pos_seq + SEQ_ELEMS;      // 25,600,000

  // ---- workspace layout (bytes) ----
  char* ws = (char*)d_ws;
  uint32_t* hdr     = (uint32_t*)(ws + 0);        // 16 u32
  uint32_t* degcnt  = (uint32_t*)(ws + 64);       // 50000 u32; reused as radix offs
  uint32_t* cursor2 = (uint32_t*)(ws + 200064);   // 50000 u32; reused as radix hist
  float*    sumbuf  = (float*)   (ws + 400064);   // 128
  uint32_t* rowptr  = (uint32_t*)(ws + 400576);   // 50001
  uint32_t* colsrc  = (uint32_t*)(ws + 600592);   // 800000
  float*    dinv    = (float*)   (ws + 3800592);  // 50000
  uint32_t* kA      = (uint32_t*)(ws + 4000592);  // 50000
  uint32_t* vB      = (uint32_t*)(ws + 4200592);  // 50000
  uint32_t* kB      = (uint32_t*)(ws + 4400592);  // 50000
  uint32_t* vA      = (uint32_t*)(ws + 4600592);  // 50000 (final perm)
  uint32_t* blksum  = (uint32_t*)(ws + 4800592);  // 256
  uint16_t* BT      = (uint16_t*)(ws + 4801664);  // 128*512 bf16 = 131072 B
  float*    hw_pos  = (float*)   (ws + 5000592);  // 6,400,000
  float*    hw_neg  = (float*)   (ws + 30600592); // 6,400,000

  uint32_t* rs_hist = cursor2;
  uint32_t* rs_offs = degcnt;

  hipMemsetAsync(ws + 64, 0, 400576 - 64, stream);

  setup_keys_kernel<<<1, 64, 0, stream>>>(pprob, hdr);
  wt_bf16_kernel<<<DIN / 32, 256, 0, stream>>>(W, BT);

  dropout_kernel<<<(unsigned)(SEQ_ELEMS / 4 / 256), 256, 0, stream>>>(x, out_pos_seq, hdr, 0, SEQ_ELEMS / 4);
  dropout_kernel<<<(unsigned)(SEQ_ELEMS / 4 / 256), 256, 0, stream>>>(x, out_neg_seq, hdr, 2, SEQ_ELEMS / 4);

  deg_count_kernel<<<(N_EDGES + 255) / 256, 256, 0, stream>>>(ei, degcnt);
  dinv_kernel<<<(N_NODES + 255) / 256, 256, 0, stream>>>(degcnt, dinv);
  int sblocks = (N_NODES + 255) / 256;  // 196
  scan1_kernel<<<sblocks, 256, 0, stream>>>(degcnt, rowptr, blksum, N_NODES);
  scan2_kernel<<<1, 256, 0, stream>>>(blksum, sblocks);
  scan3_kernel<<<sblocks, 256, 0, stream>>>(rowptr, blksum, N_NODES);
  fill_kernel<<<(N_EDGES + 255) / 256, 256, 0, stream>>>(ei, rowptr, cursor2, colsrc);

  // hw = seq @ W via bf16 MFMA (grid: 782 M-tiles of 64 rows)
  int gblocks = (N_NODES + 63) / 64;
  gemm_bf16_kernel<<<gblocks, 256, 0, stream>>>(out_pos_seq, BT, hw_pos, N_NODES);
  gemm_bf16_kernel<<<gblocks, 256, 0, stream>>>(out_neg_seq, BT, hw_neg, N_NODES);

  // ---- permutation: 2 rounds of stable radix sort by fresh random keys ----
  int pblocks = (N_NODES + 255) / 256;
  permkeys_kernel<<<pblocks, 256, 0, stream>>>(hdr, 4, kA, vA, N_NODES);
  for (int round = 0; round < 2; ++round) {
    if (round == 1)
      permkeys_kernel<<<pblocks, 256, 0, stream>>>(hdr, 6, kA, nullptr, N_NODES);
    for (int pass = 0; pass < 4; ++pass) {
      int shift = pass * 8;
      const uint32_t* ki = (pass & 1) ? kB : kA;
      const uint32_t* vi = (pass & 1) ? vB : vA;
      uint32_t* ko = (pass & 1) ? kA : kB;
      uint32_t* vo = (pass & 1) ? vA : vB;
      rs_hist_kernel<<<RS_NBLOCKS, RS_BLOCK, 0, stream>>>(ki, rs_hist, N_NODES, shift);
      rs_scan_kernel<<<1, 256, 0, stream>>>(rs_hist, rs_offs, RS_NBLOCKS);
      rs_scatter_kernel<<<RS_NBLOCKS, RS_BLOCK, 0, stream>>>(ki, vi, rs_offs, ko, vo, N_NODES, shift);
    }
  }
  const uint32_t* permv = vA;

  int gtblocks = (N_NODES + 7) / 8;  // 6250
  gcn_gather_kernel<false><<<gtblocks, 256, 0, stream>>>(hw_pos, dinv, rowptr, colsrc, nullptr, bias, out_pos_h);
  gcn_gather_kernel<true><<<gtblocks, 256, 0, stream>>>(hw_neg, dinv, rowptr, colsrc, permv, bias, out_neg_h);

  colsum_kernel<<<(N_NODES + 255) / 256, DOUT, 0, stream>>>(out_pos_h, sumbuf);
  sigmoid_kernel<<<1, DOUT, 0, stream>>>(sumbuf, out_summary);

  (void)in_sizes; (void)n_in; (void)out_size; (void)ws_size;
}

// Round 4
// 1081.411 us; speedup vs baseline: 3.3834x; 1.0612x over previous
//
#include <hip/hip_runtime.h>
#include <stdint.h>

// ---------------- problem constants ----------------
static constexpr int    N_NODES = 50000;
static constexpr int    N_EDGES = 800000;
static constexpr int    DIN     = 512;
static constexpr int    DOUT    = 128;
static constexpr size_t SEQ_ELEMS = (size_t)N_NODES * DIN;   // 25,600,000
static constexpr size_t H_ELEMS   = (size_t)N_NODES * DOUT;  //  6,400,000

// radix sort geometry
static constexpr int RS_BLOCK   = 256;
static constexpr int RS_EPT     = 4;
static constexpr int RS_TILE    = RS_BLOCK * RS_EPT;                   // 1024
static constexpr int RS_NBLOCKS = (N_NODES + RS_TILE - 1) / RS_TILE;   // 49

typedef __attribute__((ext_vector_type(8))) short bf16x8;
typedef __attribute__((ext_vector_type(4))) float f32x4;
typedef __attribute__((ext_vector_type(4))) unsigned short u16x4;

// f32 -> bf16 round-to-nearest-even
__device__ __forceinline__ uint16_t f2bf(float f) {
  uint32_t u = __float_as_uint(f);
  return (uint16_t)((u + 0x7FFFu + ((u >> 16) & 1u)) >> 16);
}
__device__ __forceinline__ float b2f(uint16_t h) {
  return __uint_as_float(((uint32_t)h) << 16);
}

// ---------------- threefry2x32 (20 rounds, JAX/Random123) ----------------
__device__ __forceinline__ uint32_t rotl32(uint32_t x, int r) {
  return (x << r) | (x >> (32 - r));
}

__device__ __forceinline__ void threefry2x32(uint32_t k0, uint32_t k1,
                                             uint32_t x0, uint32_t x1,
                                             uint32_t& o0, uint32_t& o1) {
  uint32_t ks0 = k0, ks1 = k1, ks2 = k0 ^ k1 ^ 0x1BD11BDAu;
  x0 += ks0; x1 += ks1;
#define TF_ROUND(r) { x0 += x1; x1 = rotl32(x1, (r)); x1 ^= x0; }
  TF_ROUND(13) TF_ROUND(15) TF_ROUND(26) TF_ROUND(6)
  x0 += ks1; x1 += ks2 + 1u;
  TF_ROUND(17) TF_ROUND(29) TF_ROUND(16) TF_ROUND(24)
  x0 += ks2; x1 += ks0 + 2u;
  TF_ROUND(13) TF_ROUND(15) TF_ROUND(26) TF_ROUND(6)
  x0 += ks0; x1 += ks1 + 3u;
  TF_ROUND(17) TF_ROUND(29) TF_ROUND(16) TF_ROUND(24)
  x0 += ks1; x1 += ks2 + 4u;
  TF_ROUND(13) TF_ROUND(15) TF_ROUND(26) TF_ROUND(6)
  x0 += ks2; x1 += ks0 + 5u;
#undef TF_ROUND
  o0 = x0; o1 = x1;
}

__device__ __forceinline__ uint32_t randbits32(uint32_t k0, uint32_t k1, uint32_t ctr) {
  uint32_t a, b;
  threefry2x32(k0, k1, 0u, ctr, a, b);
  return a ^ b;
}

// ---------------- key setup ----------------
__global__ void setup_keys_kernel(const float* __restrict__ pprob, uint32_t* __restrict__ hdr) {
  if (threadIdx.x != 0 || blockIdx.x != 0) return;
  const uint32_t b0 = 0u, b1 = 1u;  // threefry_seed(1) = [0, 1]
  uint32_t k1a, k1b, k2a, k2b, k3a, k3b;
  threefry2x32(b0, b1, 0u, 0u, k1a, k1b);
  threefry2x32(b0, b1, 0u, 1u, k2a, k2b);
  threefry2x32(b0, b1, 0u, 2u, k3a, k3b);
  uint32_t ra, rb, s1a, s1b, s2a, s2b;
  threefry2x32(k3a, k3b, 0u, 0u, ra, rb);   // round1 carry key
  threefry2x32(k3a, k3b, 0u, 1u, s1a, s1b); // round1 subkey
  threefry2x32(ra, rb, 0u, 1u, s2a, s2b);   // round2 subkey
  hdr[0] = k1a; hdr[1] = k1b; hdr[2] = k2a; hdr[3] = k2b;
  hdr[4] = s1a; hdr[5] = s1b; hdr[6] = s2a; hdr[7] = s2b;
  float p = pprob[0];
  hdr[8] = __float_as_uint(1.0f - p);
  hdr[9] = __float_as_uint(1.0f / (1.0f - p));
}

// ---------------- W (512x128 f32) -> BT (128x512 bf16) ----------------
__global__ void __launch_bounds__(256) wt_bf16_kernel(const float* __restrict__ W,
                                                      uint16_t* __restrict__ BT) {
  __shared__ float tile[32][129];
  int k0 = blockIdx.x * 32;
  int t = threadIdx.x;
  for (int i = t; i < 32 * 128; i += 256) {
    int k = i >> 7, n = i & 127;
    tile[k][n] = W[(size_t)(k0 + k) * DOUT + n];
  }
  __syncthreads();
  for (int i = t; i < 32 * 128; i += 256) {
    int n = i >> 5, k = i & 31;
    BT[(size_t)n * DIN + k0 + k] = f2bf(tile[k][n]);
  }
}

// ---------------- fused dropout + MFMA bf16 GEMM ----------------
// grid (Mtiles, 2): y=0 pos branch, y=1 neg branch.
// Reads x, computes dropout (threefry), writes seq (f32, required output),
// stages bf16 A-tile in LDS, MFMA vs BT, writes hw in bf16.
__global__ void __launch_bounds__(256) dg_kernel(const float* __restrict__ x,
                                                 const uint16_t* __restrict__ BT,
                                                 const uint32_t* __restrict__ hdr,
                                                 float* __restrict__ seq_pos,
                                                 float* __restrict__ seq_neg,
                                                 uint16_t* __restrict__ hw_pos,
                                                 uint16_t* __restrict__ hw_neg, int M) {
  __shared__ __align__(16) uint16_t ldsA[64 * 64];
  __shared__ __align__(16) uint16_t ldsB[128 * 64];
  const int which = blockIdx.y;
  float*    seq = which ? seq_neg : seq_pos;
  uint16_t* hwb = which ? hw_neg : hw_pos;
  const uint32_t kk0 = hdr[which * 2], kk1 = hdr[which * 2 + 1];
  const float keep_p = __uint_as_float(hdr[8]);
  const float scale  = __uint_as_float(hdr[9]);

  const int tid  = threadIdx.x;
  const int lane = tid & 63;
  const int w    = tid >> 6;
  const int wr   = w >> 1, wc = w & 1;
  const int m0   = blockIdx.x * 64;
  const int l15  = lane & 15, l4 = lane >> 4;
  const int lr   = lane >> 3, lk = (lane & 7) * 8;

  f32x4 acc[2][4] = {};

  for (int k0 = 0; k0 < DIN; k0 += 64) {
    // B tile: async global->LDS
#pragma unroll
    for (int s = 0; s < 4; ++s) {
      int nbase = w * 32 + s * 8;
      const uint16_t* gp = BT + (size_t)(nbase + lr) * DIN + k0 + lk;
      __builtin_amdgcn_global_load_lds(
          (const __attribute__((address_space(1))) void*)gp,
          (__attribute__((address_space(3))) void*)(ldsB + nbase * 64), 16, 0, 0);
    }
    // A tile: load x, dropout, write seq, stage bf16
#pragma unroll
    for (int i = 0; i < 4; ++i) {
      int idx = tid + i * 256;
      int row = idx >> 4, q = idx & 15;
      int grow = m0 + row;
      bool valid = grow < M;
      int crow = valid ? grow : (M - 1);
      float4 v = *reinterpret_cast<const float4*>(x + (size_t)crow * DIN + k0 + q * 4);
      float r[4] = {v.x, v.y, v.z, v.w};
      uint32_t cbase = (uint32_t)crow * DIN + k0 + q * 4;
#pragma unroll
      for (int j = 0; j < 4; ++j) {
        uint32_t bits = randbits32(kk0, kk1, cbase + j);
        float u = __uint_as_float((bits >> 9) | 0x3f800000u) - 1.0f;
        r[j] = (u < keep_p) ? r[j] * scale : 0.0f;
      }
      if (valid)
        *reinterpret_cast<float4*>(seq + (size_t)grow * DIN + k0 + q * 4) =
            make_float4(r[0], r[1], r[2], r[3]);
      u16x4 h;
      h.x = f2bf(r[0]); h.y = f2bf(r[1]); h.z = f2bf(r[2]); h.w = f2bf(r[3]);
      *reinterpret_cast<u16x4*>(ldsA + row * 64 + q * 4) = h;
    }
    asm volatile("s_waitcnt vmcnt(0)" ::: "memory");
    __syncthreads();
#pragma unroll
    for (int kk = 0; kk < 2; ++kk) {
      bf16x8 afr[2], bfr[4];
#pragma unroll
      for (int f = 0; f < 2; ++f)
        afr[f] = *reinterpret_cast<const bf16x8*>(ldsA + (wr * 32 + f * 16 + l15) * 64 + kk * 32 + l4 * 8);
#pragma unroll
      for (int f = 0; f < 4; ++f)
        bfr[f] = *reinterpret_cast<const bf16x8*>(ldsB + (wc * 64 + f * 16 + l15) * 64 + kk * 32 + l4 * 8);
#pragma unroll
      for (int fm = 0; fm < 2; ++fm)
#pragma unroll
        for (int fn = 0; fn < 4; ++fn)
          acc[fm][fn] = __builtin_amdgcn_mfma_f32_16x16x32_bf16(afr[fm], bfr[fn], acc[fm][fn], 0, 0, 0);
    }
    __syncthreads();
  }
  // C/D layout: row = (lane>>4)*4 + r, col = lane&15
#pragma unroll
  for (int fm = 0; fm < 2; ++fm) {
#pragma unroll
    for (int r = 0; r < 4; ++r) {
      int row = m0 + wr * 32 + fm * 16 + l4 * 4 + r;
      if (row < M) {
        uint16_t* cp = hwb + (size_t)row * DOUT + wc * 64 + l15;
#pragma unroll
        for (int fn = 0; fn < 4; ++fn)
          cp[fn * 16] = f2bf(acc[fm][fn][r]);
      }
    }
  }
}

// ---------------- degree histogram / dinv / CSR ----------------
__global__ void deg_count_kernel(const int* __restrict__ ei, uint32_t* __restrict__ degcnt) {
  int e = blockIdx.x * blockDim.x + threadIdx.x;
  if (e >= N_EDGES) return;
  int d = ei[N_EDGES + e];  // dst
  atomicAdd(&degcnt[d], 1u);
}

__global__ void dinv_kernel(const uint32_t* __restrict__ degcnt, float* __restrict__ dinv) {
  int n = blockIdx.x * blockDim.x + threadIdx.x;
  if (n >= N_NODES) return;
  float deg = (float)(degcnt[n] + 1u);  // + self loop
  dinv[n] = 1.0f / sqrtf(deg);
}

// hierarchical exclusive scan over degcnt -> rowptr
__global__ void __launch_bounds__(256) scan1_kernel(const uint32_t* __restrict__ cnt,
                                                    uint32_t* __restrict__ excl,
                                                    uint32_t* __restrict__ blksum, int n) {
  __shared__ uint32_t s[256];
  int t = threadIdx.x;
  int i = blockIdx.x * 256 + t;
  uint32_t v = (i < n) ? cnt[i] : 0u;
  s[t] = v;
  __syncthreads();
  for (int off = 1; off < 256; off <<= 1) {
    uint32_t xx = (t >= off) ? s[t - off] : 0u;
    __syncthreads();
    s[t] += xx;
    __syncthreads();
  }
  if (i < n) excl[i] = s[t] - v;
  if (t == 255) blksum[blockIdx.x] = s[255];
}

__global__ void __launch_bounds__(256) scan2_kernel(uint32_t* __restrict__ blksum, int nb) {
  __shared__ uint32_t s[256];
  int t = threadIdx.x;
  uint32_t v = (t < nb) ? blksum[t] : 0u;
  s[t] = v;
  __syncthreads();
  for (int off = 1; off < 256; off <<= 1) {
    uint32_t xx = (t >= off) ? s[t - off] : 0u;
    __syncthreads();
    s[t] += xx;
    __syncthreads();
  }
  if (t < nb) blksum[t] = s[t] - v;  // exclusive block offsets
}

__global__ void __launch_bounds__(256) scan3_kernel(uint32_t* __restrict__ excl,
                                                    const uint32_t* __restrict__ blkoff, int n) {
  int i = blockIdx.x * 256 + threadIdx.x;
  if (i < n) excl[i] += blkoff[i >> 8];
  if (i == 0) excl[n] = (uint32_t)N_EDGES;
}

__global__ void fill_kernel(const int* __restrict__ ei, const uint32_t* __restrict__ rowptr,
                            uint32_t* __restrict__ cursor, uint32_t* __restrict__ colsrc) {
  int e = blockIdx.x * blockDim.x + threadIdx.x;
  if (e >= N_EDGES) return;
  int s = ei[e];
  int d = ei[N_EDGES + e];
  uint32_t pos = rowptr[d] + atomicAdd(&cursor[d], 1u);
  colsrc[pos] = (uint32_t)s;
}

// ---------------- radix: fused keygen + pass-0 histogram ----------------
template <bool WRITE_IOTA>
__global__ void __launch_bounds__(RS_BLOCK) permhist_kernel(const uint32_t* __restrict__ hdr,
                                                            int keyoff,
                                                            uint32_t* __restrict__ keys,
                                                            uint32_t* __restrict__ iota,
                                                            uint32_t* __restrict__ hist, int n) {
  __shared__ uint32_t h[256];
  int t = threadIdx.x;
  h[t] = 0;
  __syncthreads();
  uint32_t k0 = hdr[keyoff], k1 = hdr[keyoff + 1];
  int base = blockIdx.x * RS_TILE;
#pragma unroll
  for (int i = 0; i < RS_EPT; ++i) {
    int p = base + t + i * RS_BLOCK;
    if (p < n) {
      uint32_t kv = randbits32(k0, k1, (uint32_t)p);
      keys[p] = kv;
      if (WRITE_IOTA) iota[p] = (uint32_t)p;
      atomicAdd(&h[kv & 255u], 1u);
    }
  }
  __syncthreads();
  hist[t * gridDim.x + blockIdx.x] = h[t];
}

// scan hist -> offs; also zero histN for the next pass's fused accumulation
__global__ void __launch_bounds__(256) rs_scan_kernel(const uint32_t* __restrict__ hist,
                                                      uint32_t* __restrict__ offs,
                                                      uint32_t* __restrict__ histN, int nblocks) {
  __shared__ uint32_t s[256];
  int d = threadIdx.x;
  uint32_t sum = 0;
  for (int b = 0; b < nblocks; ++b) sum += hist[d * nblocks + b];
  s[d] = sum;
  __syncthreads();
  for (int off = 1; off < 256; off <<= 1) {
    uint32_t t = (d >= off) ? s[d - off] : 0u;
    __syncthreads();
    s[d] += t;
    __syncthreads();
  }
  uint32_t run = s[d] - sum;
  for (int b = 0; b < nblocks; ++b) {
    uint32_t h = hist[d * nblocks + b];
    offs[d * nblocks + b] = run;
    run += h;
  }
  for (int i = d; i < 256 * nblocks; i += 256) histN[i] = 0;
}

// stable scatter; optionally accumulate next-pass histogram (digit-major by output tile)
template <bool ACC_NEXT>
__global__ void __launch_bounds__(RS_BLOCK) rs_scatter_kernel(const uint32_t* __restrict__ keys,
                                                              const uint32_t* __restrict__ vals,
                                                              const uint32_t* __restrict__ offs,
                                                              uint32_t* __restrict__ keys_out,
                                                              uint32_t* __restrict__ vals_out,
                                                              uint32_t* __restrict__ histN,
                                                              int n, int shift) {
  __shared__ uint16_t dig[RS_TILE];
  int t = threadIdx.x;
  int base = blockIdx.x * RS_TILE;
  uint32_t myk[RS_EPT];
  uint32_t myd[RS_EPT];
#pragma unroll
  for (int i = 0; i < RS_EPT; ++i) {
    int p = base + t + i * RS_BLOCK;
    if (p < n) {
      myk[i] = keys[p];
      myd[i] = (myk[i] >> shift) & 255u;
    } else {
      myk[i] = 0u;
      myd[i] = 0xFFFFu;
    }
    dig[t + i * RS_BLOCK] = (uint16_t)myd[i];
  }
  __syncthreads();
  int rank[RS_EPT] = {0, 0, 0, 0};
  for (int j = 0; j < RS_TILE; ++j) {
    uint32_t dj = dig[j];
#pragma unroll
    for (int i = 0; i < RS_EPT; ++i) {
      rank[i] += (j < t + i * RS_BLOCK) && (dj == myd[i]);
    }
  }
#pragma unroll
  for (int i = 0; i < RS_EPT; ++i) {
    int p = base + t + i * RS_BLOCK;
    if (p < n) {
      uint32_t pos = offs[myd[i] * gridDim.x + blockIdx.x] + (uint32_t)rank[i];
      keys_out[pos] = myk[i];
      vals_out[pos] = vals[p];
      if (ACC_NEXT) {
        uint32_t dn = (myk[i] >> (shift + 8)) & 255u;
        atomicAdd(&histN[dn * gridDim.x + (pos >> 10)], 1u);
      }
    }
  }
}

// ---------------- GCN gather conv (bf16 hw, float4 cols per lane, 8 nodes/block) ----------------
// grid (nblocks, 2): y=0 pos (no perm), y=1 neg (perm)
__global__ void __launch_bounds__(256) gcn_gather_kernel(const uint16_t* __restrict__ hw_pos,
                                                         const uint16_t* __restrict__ hw_neg,
                                                         const float* __restrict__ dinv,
                                                         const uint32_t* __restrict__ rowptr,
                                                         const uint32_t* __restrict__ colsrc,
                                                         const uint32_t* __restrict__ perm,
                                                         const float* __restrict__ bias,
                                                         float* __restrict__ out_pos,
                                                         float* __restrict__ out_neg) {
  const bool use_perm = blockIdx.y != 0;
  const uint16_t* hw = use_perm ? hw_neg : hw_pos;
  float* outh = use_perm ? out_neg : out_pos;
  int node = blockIdx.x * 8 + (threadIdx.x >> 5);
  if (node >= N_NODES) return;
  int c4 = (threadIdx.x & 31) * 4;
  uint32_t e0 = rowptr[node], e1 = rowptr[node + 1];
  float ax = 0.f, ay = 0.f, az = 0.f, aw = 0.f;
  for (uint32_t e = e0; e < e1; ++e) {
    uint32_t s = colsrc[e];
    float dv = dinv[s];
    uint32_t srow = use_perm ? perm[s] : s;
    u16x4 v = *reinterpret_cast<const u16x4*>(hw + (size_t)srow * DOUT + c4);
    ax += b2f(v.x) * dv; ay += b2f(v.y) * dv; az += b2f(v.z) * dv; aw += b2f(v.w) * dv;
  }
  float dn = dinv[node];
  uint32_t nrow = use_perm ? perm[node] : (uint32_t)node;
  u16x4 sv = *reinterpret_cast<const u16x4*>(hw + (size_t)nrow * DOUT + c4);
  float4 bv = *reinterpret_cast<const float4*>(bias + c4);
  float d2 = dn * dn;
  float4 o;
  o.x = fmaxf(dn * ax + d2 * b2f(sv.x) + bv.x, 0.0f);
  o.y = fmaxf(dn * ay + d2 * b2f(sv.y) + bv.y, 0.0f);
  o.z = fmaxf(dn * az + d2 * b2f(sv.z) + bv.z, 0.0f);
  o.w = fmaxf(dn * aw + d2 * b2f(sv.w) + bv.w, 0.0f);
  *reinterpret_cast<float4*>(outh + (size_t)node * DOUT + c4) = o;
}

// ---------------- summary ----------------
__global__ void colsum_kernel(const float* __restrict__ ph, float* __restrict__ sumbuf) {
  int c = threadIdx.x;
  int r0 = blockIdx.x * 256;
  int r1 = r0 + 256; if (r1 > N_NODES) r1 = N_NODES;
  float s = 0.0f;
  for (int r = r0; r < r1; ++r) s += ph[(size_t)r * DOUT + c];
  atomicAdd(&sumbuf[c], s);
}

__global__ void sigmoid_kernel(const float* __restrict__ sumbuf, float* __restrict__ outs) {
  int c = threadIdx.x;
  if (c >= DOUT) return;
  float m = sumbuf[c] * (1.0f / (float)N_NODES);
  outs[c] = 1.0f / (1.0f + expf(-m));
}

// ---------------- launch ----------------
extern "C" void kernel_launch(void* const* d_in, const int* in_sizes, int n_in,
                              void* d_out, int out_size, void* d_ws, size_t ws_size,
                              hipStream_t stream) {
  const float* x     = (const float*)d_in[0];
  const int*   ei    = (const int*)d_in[1];
  const float* W     = (const float*)d_in[2];
  const float* bias  = (const float*)d_in[3];
  const float* pprob = (const float*)d_in[4];

  float* out = (float*)d_out;
  float* out_pos_h   = out;                          // 6,400,000
  float* out_neg_h   = out + H_ELEMS;                // 6,400,000
  float* out_summary = out + 2 * H_ELEMS;            // 128
  float* out_pos_seq = out + 2 * H_ELEMS + DOUT;     // 25,600,000
  float* out_neg_seq = out_pos_seq + SEQ_ELEMS;      // 25,600,000

  // ---- workspace layout (bytes) ----
  char* ws = (char*)d_ws;
  uint32_t* hdr     = (uint32_t*)(ws + 0);         // 16 u32
  uint32_t* degcnt  = (uint32_t*)(ws + 64);        // 50000 u32
  uint32_t* cursor  = (uint32_t*)(ws + 200064);    // 50000 u32
  float*    sumbuf  = (float*)   (ws + 400064);    // 128 f32
  uint32_t* histA   = (uint32_t*)(ws + 400576);    // 12544 u32
  uint32_t* histB   = (uint32_t*)(ws + 450752);    // 12544 u32
  uint32_t* offs    = (uint32_t*)(ws + 500928);    // 12544 u32
  uint32_t* rowptr  = (uint32_t*)(ws + 551168);    // 50001 u32
  uint32_t* colsrc  = (uint32_t*)(ws + 751232);    // 800000 u32
  float*    dinv    = (float*)   (ws + 3951232);   // 50000 f32
  uint32_t* kA      = (uint32_t*)(ws + 4151232);   // 50000
  uint32_t* kB      = (uint32_t*)(ws + 4351232);   // 50000
  uint32_t* vA      = (uint32_t*)(ws + 4551232);   // 50000 (final perm)
  uint32_t* vB      = (uint32_t*)(ws + 4751232);   // 50000
  uint32_t* blksum  = (uint32_t*)(ws + 4951232);   // 256
  uint16_t* BT      = (uint16_t*)(ws + 4952320);   // 128*512 bf16
  uint16_t* hw_pos  = (uint16_t*)(ws + 5083392);   // 6.4M bf16 = 12.8 MB
  uint16_t* hw_neg  = (uint16_t*)(ws + 17883392);  // 6.4M bf16
  // end ~30.7 MB

  // zero: degcnt, cursor, sumbuf (hists don't need it: permhist overwrites,
  // scan zeros the next-pass hist before scatter accumulates)
  hipMemsetAsync(ws + 64, 0, 400576 - 64, stream);

  setup_keys_kernel<<<1, 64, 0, stream>>>(pprob, hdr);
  wt_bf16_kernel<<<DIN / 32, 256, 0, stream>>>(W, BT);

  // fused dropout + GEMM, both branches
  dim3 dgrid((N_NODES + 63) / 64, 2);
  dg_kernel<<<dgrid, 256, 0, stream>>>(x, BT, hdr, out_pos_seq, out_neg_seq,
                                       hw_pos, hw_neg, N_NODES);

  // CSR build
  deg_count_kernel<<<(N_EDGES + 255) / 256, 256, 0, stream>>>(ei, degcnt);
  dinv_kernel<<<(N_NODES + 255) / 256, 256, 0, stream>>>(degcnt, dinv);
  int sblocks = (N_NODES + 255) / 256;  // 196
  scan1_kernel<<<sblocks, 256, 0, stream>>>(degcnt, rowptr, blksum, N_NODES);
  scan2_kernel<<<1, 256, 0, stream>>>(blksum, sblocks);
  scan3_kernel<<<sblocks, 256, 0, stream>>>(rowptr, blksum, N_NODES);
  fill_kernel<<<(N_EDGES + 255) / 256, 256, 0, stream>>>(ei, rowptr, cursor, colsrc);

  // ---- permutation: 2 rounds of stable radix sort (fused hist pipeline) ----
  uint32_t* H[2] = {histA, histB};
  for (int round = 0; round < 2; ++round) {
    if (round == 0)
      permhist_kernel<true><<<RS_NBLOCKS, RS_BLOCK, 0, stream>>>(hdr, 4, kA, vA, histA, N_NODES);
    else
      permhist_kernel<false><<<RS_NBLOCKS, RS_BLOCK, 0, stream>>>(hdr, 6, kA, nullptr, histA, N_NODES);
    for (int pass = 0; pass < 4; ++pass) {
      int shift = pass * 8;
      const uint32_t* ki = (pass & 1) ? kB : kA;
      const uint32_t* vi = (pass & 1) ? vB : vA;
      uint32_t* ko = (pass & 1) ? kA : kB;
      uint32_t* vo = (pass & 1) ? vA : vB;
      rs_scan_kernel<<<1, 256, 0, stream>>>(H[pass & 1], offs, H[(pass + 1) & 1], RS_NBLOCKS);
      if (pass < 3)
        rs_scatter_kernel<true><<<RS_NBLOCKS, RS_BLOCK, 0, stream>>>(
            ki, vi, offs, ko, vo, H[(pass + 1) & 1], N_NODES, shift);
      else
        rs_scatter_kernel<false><<<RS_NBLOCKS, RS_BLOCK, 0, stream>>>(
            ki, vi, offs, ko, vo, nullptr, N_NODES, shift);
    }
  }
  const uint32_t* permv = vA;

  // convs (both branches in one launch)
  dim3 ggrid2((N_NODES + 7) / 8, 2);
  gcn_gather_kernel<<<ggrid2, 256, 0, stream>>>(hw_pos, hw_neg, dinv, rowptr, colsrc,
                                                permv, bias, out_pos_h, out_neg_h);

  colsum_kernel<<<(N_NODES + 255) / 256, DOUT, 0, stream>>>(out_pos_h, sumbuf);
  sigmoid_kernel<<<1, DOUT, 0, stream>>>(sumbuf, out_summary);

  (void)in_sizes; (void)n_in; (void)out_size; (void)ws_size;
}